// Round 5
// baseline (216.223 us; speedup 1.0000x reference)
//
#include <hip/hip_runtime.h>
#include <stdint.h>

typedef float f32x4_t __attribute__((ext_vector_type(4)));
typedef __bf16 bf16x8_t __attribute__((ext_vector_type(8)));

#define GLD16(gp, lp) __builtin_amdgcn_global_load_lds( \
    (const __attribute__((address_space(1))) void*)(gp), \
    (__attribute__((address_space(3))) void*)(lp), 16, 0, 0)

__device__ __forceinline__ uint32_t f2bf(float f) {
  uint32_t u = __float_as_uint(f);
  u += 0x7FFFu + ((u >> 16) & 1u);   // RNE
  return u >> 16;
}
__device__ __forceinline__ uint32_t pack2(float a, float b) {
  return f2bf(a) | (f2bf(b) << 16);
}

// ------------------------------------------------------------------
// build_m01: M01[a][b][r2] = sum_r1 c0[0,i1,j1,r1] * c1[r1,i2,j2,r2]
//   a = i1*16+i2 (block), b = j1*16+j2 (thread). fp32, 8 MB.
// ------------------------------------------------------------------
__global__ __launch_bounds__(256) void build_m01_kernel(
    const float* __restrict__ c0, const float* __restrict__ c1,
    float* __restrict__ M01) {
  const int a = blockIdx.x, t = threadIdx.x;
  const int i1 = a >> 4, i2 = a & 15, j1 = t >> 4, j2 = t & 15;
  const float* c0p = c0 + (i1 * 16 + j1) * 32;                   // + r1
  const float4* c1v = (const float4*)(c1 + i2 * 512 + j2 * 32);  // + r1*2048(f4) + q

  float acc[32];
  #pragma unroll
  for (int r2 = 0; r2 < 32; ++r2) acc[r2] = 0.f;

  #pragma unroll 4
  for (int r1 = 0; r1 < 32; ++r1) {
    const float g = c0p[r1];
    #pragma unroll
    for (int q = 0; q < 8; ++q) {
      const float4 v = c1v[r1 * 2048 + q];
      acc[q * 4 + 0] += g * v.x; acc[q * 4 + 1] += g * v.y;
      acc[q * 4 + 2] += g * v.z; acc[q * 4 + 3] += g * v.w;
    }
  }
  float4* dst = (float4*)(M01 + (size_t)a * 8192 + t * 32);  // 128B/thread contiguous
  #pragma unroll
  for (int q = 0; q < 8; ++q) {
    float4 v = {acc[q * 4 + 0], acc[q * 4 + 1], acc[q * 4 + 2], acc[q * 4 + 3]};
    dst[q] = v;
  }
}

// ------------------------------------------------------------------
// build_w2: W[(a,i3)][(b,j3)] = sum_r2 M01[a][b][r2] * c2[r2,i3,j3]
// 1024 blocks = (a, i3-quad); block reads its M01 row once, writes 4 W rows.
// r2 loop FULLY unrolled so M[r2] is constant-indexed (rule #20: runtime
// index -> scratch; this was the r3/r4 ~50us bug).
// ------------------------------------------------------------------
__global__ __launch_bounds__(256) void build_w2_kernel(
    const float* __restrict__ M01, const float* __restrict__ c2,
    uint16_t* __restrict__ W) {
  __shared__ float C2L[4][512];                  // [i3-slice][r2*16 + j3], 8 KB
  const int bid0 = blockIdx.x;
  const int bid = (bid0 & 7) * 128 + (bid0 >> 3);   // bijective XCD swizzle
  const int a = bid >> 2, i3q = (bid & 3) << 2;
  const int t = threadIdx.x;

  #pragma unroll
  for (int s = 0; s < 2; ++s) {                  // 512 float4 loads total
    const int idx = t * 2 + s;                   // 0..511
    const int sl = idx >> 7;                     // i3 slice 0..3
    const int rem = idx & 127;                   // r2*4 + q
    ((float4*)C2L[sl])[rem] =
        ((const float4*)c2)[(rem >> 2) * 64 + (i3q + sl) * 4 + (rem & 3)];
  }
  __syncthreads();

  float M[32];
  const float4* mp = (const float4*)(M01 + (size_t)a * 8192 + t * 32);
  #pragma unroll
  for (int q = 0; q < 8; ++q) {
    const float4 v = mp[q];
    M[q * 4 + 0] = v.x; M[q * 4 + 1] = v.y; M[q * 4 + 2] = v.z; M[q * 4 + 3] = v.w;
  }

  #pragma unroll 1
  for (int i3l = 0; i3l < 4; ++i3l) {
    float acc[16];
    #pragma unroll
    for (int j = 0; j < 16; ++j) acc[j] = 0.f;

    const float* C2s = C2L[i3l];
    #pragma unroll          // FULL unroll: M[r2] must be compile-time indexed
    for (int r2 = 0; r2 < 32; ++r2) {
      const float4* cp = (const float4*)(C2s + r2 * 16);  // uniform addr -> broadcast
      const float4 q0 = cp[0], q1 = cp[1], q2 = cp[2], q3 = cp[3];
      const float m = M[r2];
      acc[0]  += m * q0.x; acc[1]  += m * q0.y; acc[2]  += m * q0.z; acc[3]  += m * q0.w;
      acc[4]  += m * q1.x; acc[5]  += m * q1.y; acc[6]  += m * q1.z; acc[7]  += m * q1.w;
      acc[8]  += m * q2.x; acc[9]  += m * q2.y; acc[10] += m * q2.z; acc[11] += m * q2.w;
      acc[12] += m * q3.x; acc[13] += m * q3.y; acc[14] += m * q3.z; acc[15] += m * q3.w;
    }

    uint4 o0, o1;
    o0.x = pack2(acc[0],  acc[1]);  o0.y = pack2(acc[2],  acc[3]);
    o0.z = pack2(acc[4],  acc[5]);  o0.w = pack2(acc[6],  acc[7]);
    o1.x = pack2(acc[8],  acc[9]);  o1.y = pack2(acc[10], acc[11]);
    o1.z = pack2(acc[12], acc[13]); o1.w = pack2(acc[14], acc[15]);
    uint4* dst = (uint4*)(W + (size_t)(a * 16 + i3q + i3l) * 4096 + t * 16);
    dst[0] = o0; dst[1] = o1;                    // 32B/thread, row coalesced
  }
}

// ------------------------------------------------------------------
// cvt_x: fp32 -> bf16, 8 elems/thread, vectorized
// ------------------------------------------------------------------
__global__ __launch_bounds__(256) void cvt_x_kernel(const float* __restrict__ x,
                                                    uint32_t* __restrict__ xb) {
  const int i = blockIdx.x * 256 + threadIdx.x;   // 524288 threads total
  const float4* x4 = (const float4*)x;
  const float4 a = x4[2 * i], b = x4[2 * i + 1];
  uint4 o;
  o.x = pack2(a.x, a.y); o.y = pack2(a.z, a.w);
  o.z = pack2(b.x, b.y); o.w = pack2(b.z, b.w);
  ((uint4*)xb)[i] = o;
}

// ------------------------------------------------------------------
// GEMM: C[1024,4096] = A(bf16) * Bt(bf16,(n,k))^T + bias
// BM=128 BN=128 BK=64, 4 waves, wave tile 64x64 (4x4 acc) -> 1.5x fewer
// LDS b128 reads per FLOP vs 32x64 (the r4 bottleneck: 96 b128*12cyc ~1150cyc
// vs 160cyc MFMA per CU per K-step). Grid 256 = 1 block/CU, so double-buffer
// LDS (stage-next-first, one barrier/step) to cover load latency in-block.
// XOR-swizzled LDS (pre-swizzled global source + swizzled ds_read).
// ------------------------------------------------------------------
__global__ __launch_bounds__(256, 1) void gemm_bt_bias_kernel(
    const uint16_t* __restrict__ A, const uint16_t* __restrict__ Bt,
    const float* __restrict__ bias, float* __restrict__ C) {
  constexpr int Kd = 4096, Nd = 4096;
  __shared__ uint16_t As[2][128 * 64];   // 2 x 16 KB
  __shared__ uint16_t Bs[2][128 * 64];   // 2 x 16 KB
  const int t = threadIdx.x;
  const int wid = t >> 6, lane = t & 63;

  // XCD-grouped mapping: XCD g owns n-tiles [4g,4g+4) x 8 m-tiles (32 blocks)
  const int bid = blockIdx.x;
  const int g = bid & 7, idx = bid >> 3;          // idx 0..31
  const int ntile = g * 4 + (idx >> 3);           // 0..31
  const int mtile = idx & 7;                      // 0..7
  const int brow = mtile * 128, bcol = ntile * 128;

  // staging: chunk_id = t + 256*call covers row = rb + 32*call, chunk t&7.
  // (rb+32i)&7 == rb&7, so the swizzled source column ce is call-invariant.
  const int rb = t >> 3;                                  // 0..31
  const int ce = ((t & 7) * 8) ^ ((rb & 7) << 3);
  const uint16_t* gA = A + (size_t)(brow + rb) * Kd + ce;
  const uint16_t* gB = Bt + (size_t)(bcol + rb) * Kd + ce;
  const int wofs = wid * 512;                             // elements

  const int wm = wid >> 1, wn = wid & 1;                  // wave tile (wm*64, wn*64)
  const int fr = lane & 15, fk = (lane >> 4) * 8;
  const int csw = (fr & 7) << 3;                          // read-side swizzle

  f32x4_t zero = {0.f, 0.f, 0.f, 0.f};
  f32x4_t acc[4][4];
  #pragma unroll
  for (int m = 0; m < 4; ++m)
    #pragma unroll
    for (int n = 0; n < 4; ++n) acc[m][n] = zero;

  #define STAGE(buf, kt)                                                      \
    do {                                                                      \
      _Pragma("unroll")                                                       \
      for (int i = 0; i < 4; ++i) {                                           \
        GLD16(gA + (size_t)i * 32 * Kd + (kt), As[buf] + i * 2048 + wofs);    \
        GLD16(gB + (size_t)i * 32 * Kd + (kt), Bs[buf] + i * 2048 + wofs);    \
      }                                                                       \
    } while (0)

  STAGE(0, 0);
  __syncthreads();

  int cur = 0;
  for (int kt = 0; kt < Kd; kt += 64) {
    if (kt + 64 < Kd) STAGE(cur ^ 1, kt + 64);   // issue next tile first

    bf16x8_t af[2][4], bfr[2][4];
    #pragma unroll
    for (int kk = 0; kk < 2; ++kk) {
      const int col = (kk * 32 + fk) ^ csw;
      #pragma unroll
      for (int m = 0; m < 4; ++m)
        af[kk][m] = *(const bf16x8_t*)(As[cur] + (wm * 64 + m * 16 + fr) * 64 + col);
      #pragma unroll
      for (int n = 0; n < 4; ++n)
        bfr[kk][n] = *(const bf16x8_t*)(Bs[cur] + (wn * 64 + n * 16 + fr) * 64 + col);
    }
    #pragma unroll
    for (int kk = 0; kk < 2; ++kk)
      #pragma unroll
      for (int m = 0; m < 4; ++m)
        #pragma unroll
        for (int n = 0; n < 4; ++n)
          acc[m][n] = __builtin_amdgcn_mfma_f32_16x16x32_bf16(
              af[kk][m], bfr[kk][n], acc[m][n], 0, 0, 0);

    __syncthreads();   // next-stage writes land; cur reads complete
    cur ^= 1;
  }
  #undef STAGE

  // epilogue: C/D layout col=lane&15, row=(lane>>4)*4+reg (m89/m91)
  const int orow = brow + wm * 64 + (lane >> 4) * 4;
  const int ocol = bcol + wn * 64 + fr;
  #pragma unroll
  for (int n = 0; n < 4; ++n) {
    const float bv = bias[ocol + n * 16];
    #pragma unroll
    for (int m = 0; m < 4; ++m) {
      float* Cp = C + (size_t)(orow + m * 16) * Nd + ocol + n * 16;
      #pragma unroll
      for (int r = 0; r < 4; ++r) Cp[(size_t)r * Nd] = acc[m][n][r] + bv;
    }
  }
}

extern "C" void kernel_launch(void* const* d_in, const int* in_sizes, int n_in,
                              void* d_out, int out_size, void* d_ws, size_t ws_size,
                              hipStream_t stream) {
  const float* x    = (const float*)d_in[0];   // (1024, 4096)
  const float* c0   = (const float*)d_in[1];   // (1, 16, 16, 32)
  const float* c1   = (const float*)d_in[2];   // (32, 16, 16, 32)
  const float* c2   = (const float*)d_in[3];   // (32, 16, 16, 1)
  const float* bias = (const float*)d_in[4];   // (4096,)
  float* y = (float*)d_out;                    // (1024, 4096)

  // ws layout (40 MB):
  //   [0, 32M)   W bf16 (4096x4096)
  //   [32M, 40M) slab: M01 fp32 (kernels 1-2), then xb bf16 (kernels 3-4)
  uint16_t* W    = (uint16_t*)d_ws;
  char*     slab = (char*)d_ws + (size_t)4096 * 4096 * 2;
  float*    M01  = (float*)slab;
  uint16_t* xb   = (uint16_t*)slab;

  build_m01_kernel<<<256, 256, 0, stream>>>(c0, c1, M01);
  build_w2_kernel<<<1024, 256, 0, stream>>>(M01, c2, W);
  cvt_x_kernel<<<2048, 256, 0, stream>>>(x, (uint32_t*)xb);
  gemm_bt_bias_kernel<<<256, 256, 0, stream>>>(xb, W, bias, y);
}

// Round 7
// 196.154 us; speedup vs baseline: 1.1023x; 1.1023x over previous
//
#include <hip/hip_runtime.h>
#include <stdint.h>

typedef float f32x4_t __attribute__((ext_vector_type(4)));
typedef __bf16 bf16x8_t __attribute__((ext_vector_type(8)));

#define GLD16(gp, lp) __builtin_amdgcn_global_load_lds( \
    (const __attribute__((address_space(1))) void*)(gp), \
    (__attribute__((address_space(3))) void*)(lp), 16, 0, 0)

__device__ __forceinline__ uint32_t f2bf(float f) {
  uint32_t u = __float_as_uint(f);
  u += 0x7FFFu + ((u >> 16) & 1u);   // RNE
  return u >> 16;
}
__device__ __forceinline__ uint32_t pack2(float a, float b) {
  return f2bf(a) | (f2bf(b) << 16);
}

// ------------------------------------------------------------------
// build_m01: M01[a][b][r2] = sum_r1 c0[0,i1,j1,r1] * c1[r1,i2,j2,r2]
//   a = i1*16+i2 (block), b = j1*16+j2 (thread). fp32, 8 MB.
// ------------------------------------------------------------------
__global__ __launch_bounds__(256) void build_m01_kernel(
    const float* __restrict__ c0, const float* __restrict__ c1,
    float* __restrict__ M01) {
  const int a = blockIdx.x, t = threadIdx.x;
  const int i1 = a >> 4, i2 = a & 15, j1 = t >> 4, j2 = t & 15;
  const float* c0p = c0 + (i1 * 16 + j1) * 32;                   // + r1
  const float4* c1v = (const float4*)(c1 + i2 * 512 + j2 * 32);  // + r1*2048(f4) + q

  float acc[32];
  #pragma unroll
  for (int r2 = 0; r2 < 32; ++r2) acc[r2] = 0.f;

  #pragma unroll 4
  for (int r1 = 0; r1 < 32; ++r1) {
    const float g = c0p[r1];
    #pragma unroll
    for (int q = 0; q < 8; ++q) {
      const float4 v = c1v[r1 * 2048 + q];
      acc[q * 4 + 0] += g * v.x; acc[q * 4 + 1] += g * v.y;
      acc[q * 4 + 2] += g * v.z; acc[q * 4 + 3] += g * v.w;
    }
  }
  float4* dst = (float4*)(M01 + (size_t)a * 8192 + t * 32);  // 128B/thread contiguous
  #pragma unroll
  for (int q = 0; q < 8; ++q) {
    float4 v = {acc[q * 4 + 0], acc[q * 4 + 1], acc[q * 4 + 2], acc[q * 4 + 3]};
    dst[q] = v;
  }
}

// ------------------------------------------------------------------
// build_w2: W[(a,i3)][(b,j3)] = sum_r2 M01[a][b][r2] * c2[r2,i3,j3]
// 1024 blocks = (a, i3-quad); block reads its M01 row once, writes 4 W rows.
// r2 loop FULLY unrolled (rule #20: runtime index into M[] -> scratch).
// ------------------------------------------------------------------
__global__ __launch_bounds__(256) void build_w2_kernel(
    const float* __restrict__ M01, const float* __restrict__ c2,
    uint16_t* __restrict__ W) {
  __shared__ float C2L[4][512];                  // [i3-slice][r2*16 + j3], 8 KB
  const int bid0 = blockIdx.x;
  const int bid = (bid0 & 7) * 128 + (bid0 >> 3);   // bijective XCD swizzle
  const int a = bid >> 2, i3q = (bid & 3) << 2;
  const int t = threadIdx.x;

  #pragma unroll
  for (int s = 0; s < 2; ++s) {                  // 512 float4 loads total
    const int idx = t * 2 + s;                   // 0..511
    const int sl = idx >> 7;                     // i3 slice 0..3
    const int rem = idx & 127;                   // r2*4 + q
    ((float4*)C2L[sl])[rem] =
        ((const float4*)c2)[(rem >> 2) * 64 + (i3q + sl) * 4 + (rem & 3)];
  }
  __syncthreads();

  float M[32];
  const float4* mp = (const float4*)(M01 + (size_t)a * 8192 + t * 32);
  #pragma unroll
  for (int q = 0; q < 8; ++q) {
    const float4 v = mp[q];
    M[q * 4 + 0] = v.x; M[q * 4 + 1] = v.y; M[q * 4 + 2] = v.z; M[q * 4 + 3] = v.w;
  }

  #pragma unroll 1
  for (int i3l = 0; i3l < 4; ++i3l) {
    float acc[16];
    #pragma unroll
    for (int j = 0; j < 16; ++j) acc[j] = 0.f;

    const float* C2s = C2L[i3l];
    #pragma unroll          // FULL unroll: M[r2] must be compile-time indexed
    for (int r2 = 0; r2 < 32; ++r2) {
      const float4* cp = (const float4*)(C2s + r2 * 16);  // uniform addr -> broadcast
      const float4 q0 = cp[0], q1 = cp[1], q2 = cp[2], q3 = cp[3];
      const float m = M[r2];
      acc[0]  += m * q0.x; acc[1]  += m * q0.y; acc[2]  += m * q0.z; acc[3]  += m * q0.w;
      acc[4]  += m * q1.x; acc[5]  += m * q1.y; acc[6]  += m * q1.z; acc[7]  += m * q1.w;
      acc[8]  += m * q2.x; acc[9]  += m * q2.y; acc[10] += m * q2.z; acc[11] += m * q2.w;
      acc[12] += m * q3.x; acc[13] += m * q3.y; acc[14] += m * q3.z; acc[15] += m * q3.w;
    }

    uint4 o0, o1;
    o0.x = pack2(acc[0],  acc[1]);  o0.y = pack2(acc[2],  acc[3]);
    o0.z = pack2(acc[4],  acc[5]);  o0.w = pack2(acc[6],  acc[7]);
    o1.x = pack2(acc[8],  acc[9]);  o1.y = pack2(acc[10], acc[11]);
    o1.z = pack2(acc[12], acc[13]); o1.w = pack2(acc[14], acc[15]);
    uint4* dst = (uint4*)(W + (size_t)(a * 16 + i3q + i3l) * 4096 + t * 16);
    dst[0] = o0; dst[1] = o1;                    // 32B/thread, row coalesced
  }
}

// ------------------------------------------------------------------
// cvt_x: fp32 -> bf16, 8 elems/thread, vectorized
// ------------------------------------------------------------------
__global__ __launch_bounds__(256) void cvt_x_kernel(const float* __restrict__ x,
                                                    uint32_t* __restrict__ xb) {
  const int i = blockIdx.x * 256 + threadIdx.x;   // 524288 threads total
  const float4* x4 = (const float4*)x;
  const float4 a = x4[2 * i], b = x4[2 * i + 1];
  uint4 o;
  o.x = pack2(a.x, a.y); o.y = pack2(a.z, a.w);
  o.z = pack2(b.x, b.y); o.w = pack2(b.z, b.w);
  ((uint4*)xb)[i] = o;
}

// ------------------------------------------------------------------
// GEMM split-K=2: BM=128 BN=128 BK=64, 4 waves, wave tile 64x64 (the r5
// FLOP/LDS-read win) BUT grid = 8 mtiles x 32 ntiles x 2 k-halves = 512
// blocks = 2 blocks/CU = 8 waves/CU (the r5 failure was 1 block/CU: no
// wave to cover the barrier drain). ks=0 writes raw fp32 to P0 (=y),
// ks=1 to P1 (ws); reduce adds them + bias. dbuf stage-ahead loop.
// ------------------------------------------------------------------
__global__ __launch_bounds__(256, 2) void gemm_splitk_kernel(
    const uint16_t* __restrict__ A, const uint16_t* __restrict__ Bt,
    float* __restrict__ P0, float* __restrict__ P1) {
  constexpr int Kd = 4096, Nd = 4096;
  __shared__ uint16_t As[2][128 * 64];   // 2 x 16 KB
  __shared__ uint16_t Bs[2][128 * 64];   // 2 x 16 KB
  const int t = threadIdx.x;
  const int wid = t >> 6, lane = t & 63;

  // XCD g owns n-tiles [4g,4g+4) x 8 mtiles x 2 ks = 64 blocks
  const int bid = blockIdx.x;
  const int g = bid & 7, idx = bid >> 3;          // idx 0..63
  const int ntile = g * 4 + (idx >> 4);           // 0..31
  const int mtile = (idx >> 1) & 7;               // 0..7
  const int ks = idx & 1;                         // K half
  const int brow = mtile * 128, bcol = ntile * 128;
  const int kbase = ks * 2048;

  const int rb = t >> 3;                                  // 0..31
  const int ce = ((t & 7) * 8) ^ ((rb & 7) << 3);         // pre-swizzled src col
  const uint16_t* gA = A + (size_t)(brow + rb) * Kd + kbase + ce;
  const uint16_t* gB = Bt + (size_t)(bcol + rb) * Kd + kbase + ce;
  const int wofs = wid * 512;                             // elements

  const int wm = wid >> 1, wn = wid & 1;                  // wave tile (wm*64, wn*64)
  const int fr = lane & 15, fk = (lane >> 4) * 8;
  const int csw = (fr & 7) << 3;                          // read-side swizzle

  f32x4_t zero = {0.f, 0.f, 0.f, 0.f};
  f32x4_t acc[4][4];
  #pragma unroll
  for (int m = 0; m < 4; ++m)
    #pragma unroll
    for (int n = 0; n < 4; ++n) acc[m][n] = zero;

  #define STAGE(buf, kt)                                                      \
    do {                                                                      \
      _Pragma("unroll")                                                       \
      for (int i = 0; i < 4; ++i) {                                           \
        GLD16(gA + (size_t)i * 32 * Kd + (kt), As[buf] + i * 2048 + wofs);    \
        GLD16(gB + (size_t)i * 32 * Kd + (kt), Bs[buf] + i * 2048 + wofs);    \
      }                                                                       \
    } while (0)

  STAGE(0, 0);
  __syncthreads();

  int cur = 0;
  for (int kt = 0; kt < 2048; kt += 64) {
    if (kt + 64 < 2048) STAGE(cur ^ 1, kt + 64);   // issue next tile first

    bf16x8_t af[2][4], bfr[2][4];
    #pragma unroll
    for (int kk = 0; kk < 2; ++kk) {
      const int col = (kk * 32 + fk) ^ csw;
      #pragma unroll
      for (int m = 0; m < 4; ++m)
        af[kk][m] = *(const bf16x8_t*)(As[cur] + (wm * 64 + m * 16 + fr) * 64 + col);
      #pragma unroll
      for (int n = 0; n < 4; ++n)
        bfr[kk][n] = *(const bf16x8_t*)(Bs[cur] + (wn * 64 + n * 16 + fr) * 64 + col);
    }
    #pragma unroll
    for (int kk = 0; kk < 2; ++kk)
      #pragma unroll
      for (int m = 0; m < 4; ++m)
        #pragma unroll
        for (int n = 0; n < 4; ++n)
          acc[m][n] = __builtin_amdgcn_mfma_f32_16x16x32_bf16(
              af[kk][m], bfr[kk][n], acc[m][n], 0, 0, 0);

    __syncthreads();
    cur ^= 1;
  }
  #undef STAGE

  float* P = ks ? P1 : P0;
  const int orow = brow + wm * 64 + (lane >> 4) * 4;
  const int ocol = bcol + wn * 64 + fr;
  #pragma unroll
  for (int n = 0; n < 4; ++n) {
    #pragma unroll
    for (int m = 0; m < 4; ++m) {
      float* Cp = P + (size_t)(orow + m * 16) * Nd + ocol + n * 16;
      #pragma unroll
      for (int r = 0; r < 4; ++r) Cp[(size_t)r * Nd] = acc[m][n][r];
    }
  }
}

// ------------------------------------------------------------------
// reduce: y = y(P0) + P1 + bias. 4096 blocks x 256 thr x 1 float4.
// ------------------------------------------------------------------
__global__ __launch_bounds__(256) void reduce_kernel(
    float* __restrict__ y, const float* __restrict__ p1,
    const float* __restrict__ bias) {
  const int i4 = blockIdx.x * 256 + threadIdx.x;    // 0 .. 1048575
  const float4 a = ((const float4*)y)[i4];
  const float4 b = ((const float4*)p1)[i4];
  const float4 c = ((const float4*)bias)[i4 & 1023];  // 4096 cols / 4
  float4 o = {a.x + b.x + c.x, a.y + b.y + c.y, a.z + b.z + c.z, a.w + b.w + c.w};
  ((float4*)y)[i4] = o;
}

// ------------------------------------------------------------------
// Fallback GEMM (r4-proven, 56.6us): used only if ws_size < split-K need.
// BM=64 BN=128 BK=64, single-buffer, bias fused.
// ------------------------------------------------------------------
__global__ __launch_bounds__(256, 2) void gemm_bt_bias_kernel(
    const uint16_t* __restrict__ A, const uint16_t* __restrict__ Bt,
    const float* __restrict__ bias, float* __restrict__ C) {
  constexpr int Kd = 4096, Nd = 4096;
  __shared__ uint16_t As[64 * 64];
  __shared__ uint16_t Bs[128 * 64];
  const int t = threadIdx.x;
  const int wid = t >> 6, lane = t & 63;
  const int bid = blockIdx.x;
  const int g = bid & 7, idx = bid >> 3;
  const int ntile = g * 4 + (idx >> 4);
  const int mtile = idx & 15;
  const int brow = mtile * 64, bcol = ntile * 128;
  const uint16_t* Ab = A + (size_t)brow * Kd;
  const uint16_t* Bb = Bt + (size_t)bcol * Kd;
  const int rb = t >> 3;
  const int ce = ((t & 7) * 8) ^ ((rb & 7) << 3);
  const uint16_t* gA = Ab + (size_t)rb * Kd + ce;
  const uint16_t* gB = Bb + (size_t)rb * Kd + ce;
  uint16_t* lA0 = As + wid * 512;
  uint16_t* lA1 = As + 2048 + wid * 512;
  uint16_t* lB0 = Bs + wid * 512;
  uint16_t* lB1 = Bs + 2048 + wid * 512;
  uint16_t* lB2 = Bs + 4096 + wid * 512;
  uint16_t* lB3 = Bs + 6144 + wid * 512;
  const int wm = wid >> 1, wn = wid & 1;
  const int fr = lane & 15, fk = (lane >> 4) * 8;
  const int csw = (fr & 7) << 3;
  f32x4_t zero = {0.f, 0.f, 0.f, 0.f};
  f32x4_t acc[2][4];
  #pragma unroll
  for (int m = 0; m < 2; ++m)
    #pragma unroll
    for (int n = 0; n < 4; ++n) acc[m][n] = zero;
  for (int kt = 0; kt < Kd; kt += 64) {
    GLD16(gA + kt, lA0);
    GLD16(gA + (size_t)32 * Kd + kt, lA1);
    GLD16(gB + kt, lB0);
    GLD16(gB + (size_t)32 * Kd + kt, lB1);
    GLD16(gB + (size_t)64 * Kd + kt, lB2);
    GLD16(gB + (size_t)96 * Kd + kt, lB3);
    __syncthreads();
    bf16x8_t af[2][2], bfr[2][4];
    #pragma unroll
    for (int kk = 0; kk < 2; ++kk) {
      const int col = (kk * 32 + fk) ^ csw;
      #pragma unroll
      for (int m = 0; m < 2; ++m)
        af[kk][m] = *(const bf16x8_t*)(As + (wm * 32 + m * 16 + fr) * 64 + col);
      #pragma unroll
      for (int n = 0; n < 4; ++n)
        bfr[kk][n] = *(const bf16x8_t*)(Bs + (wn * 64 + n * 16 + fr) * 64 + col);
    }
    #pragma unroll
    for (int kk = 0; kk < 2; ++kk)
      #pragma unroll
      for (int m = 0; m < 2; ++m)
        #pragma unroll
        for (int n = 0; n < 4; ++n)
          acc[m][n] = __builtin_amdgcn_mfma_f32_16x16x32_bf16(
              af[kk][m], bfr[kk][n], acc[m][n], 0, 0, 0);
    __syncthreads();
  }
  const int orow = brow + wm * 32 + (lane >> 4) * 4;
  const int ocol = bcol + wn * 64 + fr;
  #pragma unroll
  for (int n = 0; n < 4; ++n) {
    const float bv = bias[ocol + n * 16];
    #pragma unroll
    for (int m = 0; m < 2; ++m) {
      float* Cp = C + (size_t)(orow + m * 16) * Nd + ocol + n * 16;
      #pragma unroll
      for (int r = 0; r < 4; ++r) Cp[(size_t)r * Nd] = acc[m][n][r] + bv;
    }
  }
}

extern "C" void kernel_launch(void* const* d_in, const int* in_sizes, int n_in,
                              void* d_out, int out_size, void* d_ws, size_t ws_size,
                              hipStream_t stream) {
  const float* x    = (const float*)d_in[0];   // (1024, 4096)
  const float* c0   = (const float*)d_in[1];   // (1, 16, 16, 32)
  const float* c1   = (const float*)d_in[2];   // (32, 16, 16, 32)
  const float* c2   = (const float*)d_in[3];   // (32, 16, 16, 1)
  const float* bias = (const float*)d_in[4];   // (4096,)
  float* y = (float*)d_out;                    // (1024, 4096)

  // ws layout:
  //   [0, 32M)       W bf16 (4096x4096)
  //   [32M, 40M)     slab: M01 fp32 (kernels 1-2), then xb bf16 (3+)
  //   [40M, 56.8M)   P1 fp32 partial (split-K path only)
  uint16_t* W    = (uint16_t*)d_ws;
  char*     slab = (char*)d_ws + (size_t)4096 * 4096 * 2;
  float*    M01  = (float*)slab;
  uint16_t* xb   = (uint16_t*)slab;
  float*    P1   = (float*)((char*)d_ws + (size_t)40 * 1024 * 1024);
  const size_t need = (size_t)40 * 1024 * 1024 + (size_t)1024 * 4096 * 4;

  build_m01_kernel<<<256, 256, 0, stream>>>(c0, c1, M01);
  build_w2_kernel<<<1024, 256, 0, stream>>>(M01, c2, W);
  cvt_x_kernel<<<2048, 256, 0, stream>>>(x, (uint32_t*)xb);

  if (ws_size >= need) {
    gemm_splitk_kernel<<<512, 256, 0, stream>>>(xb, W, y, P1);
    reduce_kernel<<<4096, 256, 0, stream>>>(y, P1, bias);
  } else {
    gemm_bt_bias_kernel<<<512, 256, 0, stream>>>(xb, W, bias, y);
  }
}

// Round 8
// 178.525 us; speedup vs baseline: 1.2112x; 1.0988x over previous
//
#include <hip/hip_runtime.h>
#include <stdint.h>

typedef float f32x4_t __attribute__((ext_vector_type(4)));
typedef float f32x16_t __attribute__((ext_vector_type(16)));
typedef __bf16 bf16x8_t __attribute__((ext_vector_type(8)));

#define GLD16(gp, lp) __builtin_amdgcn_global_load_lds( \
    (const __attribute__((address_space(1))) void*)(gp), \
    (__attribute__((address_space(3))) void*)(lp), 16, 0, 0)

__device__ __forceinline__ uint32_t f2bf(float f) {
  uint32_t u = __float_as_uint(f);
  u += 0x7FFFu + ((u >> 16) & 1u);   // RNE
  return u >> 16;
}
__device__ __forceinline__ uint32_t pack2(float a, float b) {
  return f2bf(a) | (f2bf(b) << 16);
}

// ------------------------------------------------------------------
// build_m01: M01[a][b][r2] = sum_r1 c0[0,i1,j1,r1] * c1[r1,i2,j2,r2]
//   a = i1*16+i2 (block), b = j1*16+j2 (thread). fp32, 8 MB.
// ------------------------------------------------------------------
__global__ __launch_bounds__(256) void build_m01_kernel(
    const float* __restrict__ c0, const float* __restrict__ c1,
    float* __restrict__ M01) {
  const int a = blockIdx.x, t = threadIdx.x;
  const int i1 = a >> 4, i2 = a & 15, j1 = t >> 4, j2 = t & 15;
  const float* c0p = c0 + (i1 * 16 + j1) * 32;                   // + r1
  const float4* c1v = (const float4*)(c1 + i2 * 512 + j2 * 32);  // + r1*2048(f4) + q

  float acc[32];
  #pragma unroll
  for (int r2 = 0; r2 < 32; ++r2) acc[r2] = 0.f;

  #pragma unroll 4
  for (int r1 = 0; r1 < 32; ++r1) {
    const float g = c0p[r1];
    #pragma unroll
    for (int q = 0; q < 8; ++q) {
      const float4 v = c1v[r1 * 2048 + q];
      acc[q * 4 + 0] += g * v.x; acc[q * 4 + 1] += g * v.y;
      acc[q * 4 + 2] += g * v.z; acc[q * 4 + 3] += g * v.w;
    }
  }
  float4* dst = (float4*)(M01 + (size_t)a * 8192 + t * 32);  // 128B/thread contiguous
  #pragma unroll
  for (int q = 0; q < 8; ++q) {
    float4 v = {acc[q * 4 + 0], acc[q * 4 + 1], acc[q * 4 + 2], acc[q * 4 + 3]};
    dst[q] = v;
  }
}

// ------------------------------------------------------------------
// build_w2 v3: W[(a,i3)][(b,j3)] = sum_r2 M01[a][b][r2] * c2[r2,i3,j3]
// r7 diagnosis: LDS-read-bound (512 ds_read_b128/thread ~= 41us/CU).
// Fix: c2 operands are WAVE-UNIFORM -> read from global with uniform
// address => s_load_dwordx16 on the SMEM pipe; FMA uses the SGPR operand
// (v_fmac v,s,v). No LDS at all. r2 FULLY unrolled (rule #20: partial
// unroll makes M[r2] runtime-indexed -> scratch).
// ------------------------------------------------------------------
__global__ __launch_bounds__(256) void build_w2_kernel(
    const float* __restrict__ M01, const float* __restrict__ c2,
    uint16_t* __restrict__ W) {
  const int bid0 = blockIdx.x;
  const int bid = (bid0 & 7) * 128 + (bid0 >> 3);   // bijective XCD swizzle
  const int a = bid >> 2, i3q = (bid & 3) << 2;
  const int t = threadIdx.x;

  float M[32];
  const float4* mp = (const float4*)(M01 + (size_t)a * 8192 + t * 32);
  #pragma unroll
  for (int q = 0; q < 8; ++q) {
    const float4 v = mp[q];
    M[q * 4 + 0] = v.x; M[q * 4 + 1] = v.y; M[q * 4 + 2] = v.z; M[q * 4 + 3] = v.w;
  }

  #pragma unroll 1
  for (int i3l = 0; i3l < 4; ++i3l) {
    const int i3 = i3q + i3l;
    const float* c2b = c2 + i3 * 16;               // + r2*256; 64B-aligned, uniform
    float acc[16];
    #pragma unroll
    for (int j = 0; j < 16; ++j) acc[j] = 0.f;

    #pragma unroll          // FULL unroll: M[r2] must stay compile-time indexed
    for (int r2 = 0; r2 < 32; ++r2) {
      const f32x16_t cv = *(const f32x16_t*)(c2b + r2 * 256);  // -> s_load_dwordx16
      const float m = M[r2];
      #pragma unroll
      for (int j = 0; j < 16; ++j) acc[j] += m * cv[j];
    }

    uint4 o0, o1;
    o0.x = pack2(acc[0],  acc[1]);  o0.y = pack2(acc[2],  acc[3]);
    o0.z = pack2(acc[4],  acc[5]);  o0.w = pack2(acc[6],  acc[7]);
    o1.x = pack2(acc[8],  acc[9]);  o1.y = pack2(acc[10], acc[11]);
    o1.z = pack2(acc[12], acc[13]); o1.w = pack2(acc[14], acc[15]);
    uint4* dst = (uint4*)(W + (size_t)(a * 16 + i3) * 4096 + t * 16);
    dst[0] = o0; dst[1] = o1;                      // 32B/thread, row coalesced
  }
}

// ------------------------------------------------------------------
// cvt_x: fp32 -> bf16, 8 elems/thread, vectorized
// ------------------------------------------------------------------
__global__ __launch_bounds__(256) void cvt_x_kernel(const float* __restrict__ x,
                                                    uint32_t* __restrict__ xb) {
  const int i = blockIdx.x * 256 + threadIdx.x;   // 524288 threads total
  const float4* x4 = (const float4*)x;
  const float4 a = x4[2 * i], b = x4[2 * i + 1];
  uint4 o;
  o.x = pack2(a.x, a.y); o.y = pack2(a.z, a.w);
  o.z = pack2(b.x, b.y); o.w = pack2(b.z, b.w);
  ((uint4*)xb)[i] = o;
}

// ------------------------------------------------------------------
// GEMM split-K=2 (r7-proven <45.7us): BM=128 BN=128 BK=64, 4 waves,
// wave tile 64x64, grid 512 = 2 blocks/CU = 8 waves/CU. ks=0 -> P0(=y),
// ks=1 -> P1; reduce adds + bias. dbuf stage-ahead loop.
// ------------------------------------------------------------------
__global__ __launch_bounds__(256, 2) void gemm_splitk_kernel(
    const uint16_t* __restrict__ A, const uint16_t* __restrict__ Bt,
    float* __restrict__ P0, float* __restrict__ P1) {
  constexpr int Kd = 4096, Nd = 4096;
  __shared__ uint16_t As[2][128 * 64];   // 2 x 16 KB
  __shared__ uint16_t Bs[2][128 * 64];   // 2 x 16 KB
  const int t = threadIdx.x;
  const int wid = t >> 6, lane = t & 63;

  // XCD g owns n-tiles [4g,4g+4) x 8 mtiles x 2 ks = 64 blocks
  const int bid = blockIdx.x;
  const int g = bid & 7, idx = bid >> 3;          // idx 0..63
  const int ntile = g * 4 + (idx >> 4);           // 0..31
  const int mtile = (idx >> 1) & 7;               // 0..7
  const int ks = idx & 1;                         // K half
  const int brow = mtile * 128, bcol = ntile * 128;
  const int kbase = ks * 2048;

  const int rb = t >> 3;                                  // 0..31
  const int ce = ((t & 7) * 8) ^ ((rb & 7) << 3);         // pre-swizzled src col
  const uint16_t* gA = A + (size_t)(brow + rb) * Kd + kbase + ce;
  const uint16_t* gB = Bt + (size_t)(bcol + rb) * Kd + kbase + ce;
  const int wofs = wid * 512;                             // elements

  const int wm = wid >> 1, wn = wid & 1;                  // wave tile (wm*64, wn*64)
  const int fr = lane & 15, fk = (lane >> 4) * 8;
  const int csw = (fr & 7) << 3;                          // read-side swizzle

  f32x4_t zero = {0.f, 0.f, 0.f, 0.f};
  f32x4_t acc[4][4];
  #pragma unroll
  for (int m = 0; m < 4; ++m)
    #pragma unroll
    for (int n = 0; n < 4; ++n) acc[m][n] = zero;

  #define STAGE(buf, kt)                                                      \
    do {                                                                      \
      _Pragma("unroll")                                                       \
      for (int i = 0; i < 4; ++i) {                                           \
        GLD16(gA + (size_t)i * 32 * Kd + (kt), As[buf] + i * 2048 + wofs);    \
        GLD16(gB + (size_t)i * 32 * Kd + (kt), Bs[buf] + i * 2048 + wofs);    \
      }                                                                       \
    } while (0)

  STAGE(0, 0);
  __syncthreads();

  int cur = 0;
  for (int kt = 0; kt < 2048; kt += 64) {
    if (kt + 64 < 2048) STAGE(cur ^ 1, kt + 64);   // issue next tile first

    bf16x8_t af[2][4], bfr[2][4];
    #pragma unroll
    for (int kk = 0; kk < 2; ++kk) {
      const int col = (kk * 32 + fk) ^ csw;
      #pragma unroll
      for (int m = 0; m < 4; ++m)
        af[kk][m] = *(const bf16x8_t*)(As[cur] + (wm * 64 + m * 16 + fr) * 64 + col);
      #pragma unroll
      for (int n = 0; n < 4; ++n)
        bfr[kk][n] = *(const bf16x8_t*)(Bs[cur] + (wn * 64 + n * 16 + fr) * 64 + col);
    }
    #pragma unroll
    for (int kk = 0; kk < 2; ++kk)
      #pragma unroll
      for (int m = 0; m < 4; ++m)
        #pragma unroll
        for (int n = 0; n < 4; ++n)
          acc[m][n] = __builtin_amdgcn_mfma_f32_16x16x32_bf16(
              af[kk][m], bfr[kk][n], acc[m][n], 0, 0, 0);

    __syncthreads();
    cur ^= 1;
  }
  #undef STAGE

  float* P = ks ? P1 : P0;
  const int orow = brow + wm * 64 + (lane >> 4) * 4;
  const int ocol = bcol + wn * 64 + fr;
  #pragma unroll
  for (int n = 0; n < 4; ++n) {
    #pragma unroll
    for (int m = 0; m < 4; ++m) {
      float* Cp = P + (size_t)(orow + m * 16) * Nd + ocol + n * 16;
      #pragma unroll
      for (int r = 0; r < 4; ++r) Cp[(size_t)r * Nd] = acc[m][n][r];
    }
  }
}

// ------------------------------------------------------------------
// reduce: y = y(P0) + P1 + bias. 4096 blocks x 256 thr x 1 float4.
// ------------------------------------------------------------------
__global__ __launch_bounds__(256) void reduce_kernel(
    float* __restrict__ y, const float* __restrict__ p1,
    const float* __restrict__ bias) {
  const int i4 = blockIdx.x * 256 + threadIdx.x;    // 0 .. 1048575
  const float4 a = ((const float4*)y)[i4];
  const float4 b = ((const float4*)p1)[i4];
  const float4 c = ((const float4*)bias)[i4 & 1023];  // 4096 cols / 4
  float4 o = {a.x + b.x + c.x, a.y + b.y + c.y, a.z + b.z + c.z, a.w + b.w + c.w};
  ((float4*)y)[i4] = o;
}

// ------------------------------------------------------------------
// Fallback GEMM (r4-proven): used only if ws_size < split-K need.
// ------------------------------------------------------------------
__global__ __launch_bounds__(256, 2) void gemm_bt_bias_kernel(
    const uint16_t* __restrict__ A, const uint16_t* __restrict__ Bt,
    const float* __restrict__ bias, float* __restrict__ C) {
  constexpr int Kd = 4096, Nd = 4096;
  __shared__ uint16_t As[64 * 64];
  __shared__ uint16_t Bs[128 * 64];
  const int t = threadIdx.x;
  const int wid = t >> 6, lane = t & 63;
  const int bid = blockIdx.x;
  const int g = bid & 7, idx = bid >> 3;
  const int ntile = g * 4 + (idx >> 4);
  const int mtile = idx & 15;
  const int brow = mtile * 64, bcol = ntile * 128;
  const uint16_t* Ab = A + (size_t)brow * Kd;
  const uint16_t* Bb = Bt + (size_t)bcol * Kd;
  const int rb = t >> 3;
  const int ce = ((t & 7) * 8) ^ ((rb & 7) << 3);
  const uint16_t* gA = Ab + (size_t)rb * Kd + ce;
  const uint16_t* gB = Bb + (size_t)rb * Kd + ce;
  uint16_t* lA0 = As + wid * 512;
  uint16_t* lA1 = As + 2048 + wid * 512;
  uint16_t* lB0 = Bs + wid * 512;
  uint16_t* lB1 = Bs + 2048 + wid * 512;
  uint16_t* lB2 = Bs + 4096 + wid * 512;
  uint16_t* lB3 = Bs + 6144 + wid * 512;
  const int wm = wid >> 1, wn = wid & 1;
  const int fr = lane & 15, fk = (lane >> 4) * 8;
  const int csw = (fr & 7) << 3;
  f32x4_t zero = {0.f, 0.f, 0.f, 0.f};
  f32x4_t acc[2][4];
  #pragma unroll
  for (int m = 0; m < 2; ++m)
    #pragma unroll
    for (int n = 0; n < 4; ++n) acc[m][n] = zero;
  for (int kt = 0; kt < Kd; kt += 64) {
    GLD16(gA + kt, lA0);
    GLD16(gA + (size_t)32 * Kd + kt, lA1);
    GLD16(gB + kt, lB0);
    GLD16(gB + (size_t)32 * Kd + kt, lB1);
    GLD16(gB + (size_t)64 * Kd + kt, lB2);
    GLD16(gB + (size_t)96 * Kd + kt, lB3);
    __syncthreads();
    bf16x8_t af[2][2], bfr[2][4];
    #pragma unroll
    for (int kk = 0; kk < 2; ++kk) {
      const int col = (kk * 32 + fk) ^ csw;
      #pragma unroll
      for (int m = 0; m < 2; ++m)
        af[kk][m] = *(const bf16x8_t*)(As + (wm * 32 + m * 16 + fr) * 64 + col);
      #pragma unroll
      for (int n = 0; n < 4; ++n)
        bfr[kk][n] = *(const bf16x8_t*)(Bs + (wn * 64 + n * 16 + fr) * 64 + col);
    }
    #pragma unroll
    for (int kk = 0; kk < 2; ++kk)
      #pragma unroll
      for (int m = 0; m < 2; ++m)
        #pragma unroll
        for (int n = 0; n < 4; ++n)
          acc[m][n] = __builtin_amdgcn_mfma_f32_16x16x32_bf16(
              af[kk][m], bfr[kk][n], acc[m][n], 0, 0, 0);
    __syncthreads();
  }
  const int orow = brow + wm * 32 + (lane >> 4) * 4;
  const int ocol = bcol + wn * 64 + fr;
  #pragma unroll
  for (int n = 0; n < 4; ++n) {
    const float bv = bias[ocol + n * 16];
    #pragma unroll
    for (int m = 0; m < 2; ++m) {
      float* Cp = C + (size_t)(orow + m * 16) * Nd + ocol + n * 16;
      #pragma unroll
      for (int r = 0; r < 4; ++r) Cp[(size_t)r * Nd] = acc[m][n][r] + bv;
    }
  }
}

extern "C" void kernel_launch(void* const* d_in, const int* in_sizes, int n_in,
                              void* d_out, int out_size, void* d_ws, size_t ws_size,
                              hipStream_t stream) {
  const float* x    = (const float*)d_in[0];   // (1024, 4096)
  const float* c0   = (const float*)d_in[1];   // (1, 16, 16, 32)
  const float* c1   = (const float*)d_in[2];   // (32, 16, 16, 32)
  const float* c2   = (const float*)d_in[3];   // (32, 16, 16, 1)
  const float* bias = (const float*)d_in[4];   // (4096,)
  float* y = (float*)d_out;                    // (1024, 4096)

  // ws layout:
  //   [0, 32M)       W bf16 (4096x4096)
  //   [32M, 40M)     slab: M01 fp32 (kernels 1-2), then xb bf16 (3+)
  //   [40M, 56.8M)   P1 fp32 partial (split-K path only)
  uint16_t* W    = (uint16_t*)d_ws;
  char*     slab = (char*)d_ws + (size_t)4096 * 4096 * 2;
  float*    M01  = (float*)slab;
  uint16_t* xb   = (uint16_t*)slab;
  float*    P1   = (float*)((char*)d_ws + (size_t)40 * 1024 * 1024);
  const size_t need = (size_t)40 * 1024 * 1024 + (size_t)1024 * 4096 * 4;

  build_m01_kernel<<<256, 256, 0, stream>>>(c0, c1, M01);
  build_w2_kernel<<<1024, 256, 0, stream>>>(M01, c2, W);
  cvt_x_kernel<<<2048, 256, 0, stream>>>(x, (uint32_t*)xb);

  if (ws_size >= need) {
    gemm_splitk_kernel<<<512, 256, 0, stream>>>(xb, W, y, P1);
    reduce_kernel<<<4096, 256, 0, stream>>>(y, P1, bias);
  } else {
    gemm_bt_bias_kernel<<<512, 256, 0, stream>>>(xb, W, bias, y);
  }
}